// Round 1
// baseline (3526.679 us; speedup 1.0000x reference)
//
#include <hip/hip_runtime.h>
#include <math.h>

#define TPB 256

// ---------------------------------------------------------------------------
// RoPE cos/sin tables, replicating JAX f32 arithmetic exactly.
// jnp.linspace(0, L, 32): step_j = fl32(j/31); mel_log[j] = fl32(L32*step_j)
// for j<31, mel_log[31] = L32 (endpoint concatenated). 10**x -> correctly
// rounded powf (glibc) == double pow rounded to f32.
// ---------------------------------------------------------------------------
__global__ __launch_bounds__(TPB) void k_tables(float* __restrict__ cosb,
                                                float* __restrict__ sinb) {
  int gid = blockIdx.x * TPB + threadIdx.x;
  if (gid >= 1024 * 32) return;
  int t = gid >> 5, j = gid & 31;
  const double Ld = 1.3222192947339193;  // python math.log10(21.0)
  float Lf = (float)Ld;
  float mlog;
  if (j == 31) {
    mlog = Lf;
  } else {
    float stepf = (float)((double)j / 31.0);
    mlog = (float)((double)Lf * (double)stepf);
  }
  float p = (float)pow(10.0, (double)mlog);
  float mel = p - 1.0f;
  float t2 = (200.0f * mel) / 1000.0f;
  float freq = 163.63636363636363f * t2;
  float ang = (float)t * freq;
  double a = (double)ang;
  cosb[gid] = (float)cos(a);
  sinb[gid] = (float)sin(a);
}

// ---------------------------------------------------------------------------
// Per-row 1/rms over D=1024 (row-major), inv[row] = rsqrt(mean(x^2)+eps)
// ---------------------------------------------------------------------------
__global__ __launch_bounds__(TPB) void k_rowinv(const float* __restrict__ X,
                                                float* __restrict__ inv) {
  __shared__ float red[4];
  int row = blockIdx.x;
  int tid = threadIdx.x;
  float4 v = *(const float4*)(X + (size_t)row * 1024 + tid * 4);
  float ss = v.x * v.x + v.y * v.y + v.z * v.z + v.w * v.w;
#pragma unroll
  for (int m = 1; m < 64; m <<= 1) ss += __shfl_xor(ss, m);
  if ((tid & 63) == 0) red[tid >> 6] = ss;
  __syncthreads();
  if (tid == 0) {
    float s = ((red[0] + red[1]) + (red[2] + red[3]));
    float mm = s * (1.0f / 1024.0f) + 1.1920928955078125e-7f;
    inv[row] = (float)(1.0 / sqrt((double)mm));
  }
}

// ---------------------------------------------------------------------------
// Tiled f32 GEMM: C = (X * inv[row] * wn[k]) @ W + bias.  M=4096, K=1024.
// mode 0: C row-major [4096][N] into o0
// mode 1: N=1024, scatter to o0[((b*16+h)*1024+t)*64+d]
// mode 2: N=2048, cols<1024 -> o0 (K), cols>=1024 -> o1 (V), same scatter
// ---------------------------------------------------------------------------
__global__ __launch_bounds__(TPB) void k_gemm(
    const float* __restrict__ X, const float* __restrict__ inv,
    const float* __restrict__ wn, const float* __restrict__ W,
    const float* __restrict__ bias, float* __restrict__ o0,
    float* __restrict__ o1, int N, int mode) {
  __shared__ float As[16][68];
  __shared__ float Bs[16][68];
  int tid = threadIdx.x;
  int bx = blockIdx.x, by = blockIdx.y;
  int tx = tid & 15, ty = tid >> 4;
  int rowa = tid >> 2, kq = (tid & 3) * 4;
  int rowb = tid >> 4, cq = (tid & 15) * 4;
  float c[4][4] = {};
  float sA = 1.0f;
  if (inv) sA = inv[by * 64 + rowa];
  const float* Xrow = X + (size_t)(by * 64 + rowa) * 1024;
  for (int k0 = 0; k0 < 1024; k0 += 16) {
    float4 a4 = *(const float4*)(Xrow + k0 + kq);
    if (wn) {
      float4 w4 = *(const float4*)(wn + k0 + kq);
      a4.x *= w4.x; a4.y *= w4.y; a4.z *= w4.z; a4.w *= w4.w;
    }
    a4.x *= sA; a4.y *= sA; a4.z *= sA; a4.w *= sA;
    As[kq + 0][rowa] = a4.x;
    As[kq + 1][rowa] = a4.y;
    As[kq + 2][rowa] = a4.z;
    As[kq + 3][rowa] = a4.w;
    float4 b4 = *(const float4*)(W + (size_t)(k0 + rowb) * N + bx * 64 + cq);
    *(float4*)&Bs[rowb][cq] = b4;
    __syncthreads();
#pragma unroll
    for (int kk = 0; kk < 16; ++kk) {
      float4 av = *(const float4*)&As[kk][ty * 4];
      float4 bv = *(const float4*)&Bs[kk][tx * 4];
      c[0][0] += av.x * bv.x; c[0][1] += av.x * bv.y;
      c[0][2] += av.x * bv.z; c[0][3] += av.x * bv.w;
      c[1][0] += av.y * bv.x; c[1][1] += av.y * bv.y;
      c[1][2] += av.y * bv.z; c[1][3] += av.y * bv.w;
      c[2][0] += av.z * bv.x; c[2][1] += av.z * bv.y;
      c[2][2] += av.z * bv.z; c[2][3] += av.z * bv.w;
      c[3][0] += av.w * bv.x; c[3][1] += av.w * bv.y;
      c[3][2] += av.w * bv.z; c[3][3] += av.w * bv.w;
    }
    __syncthreads();
  }
  float4 bb = {0.f, 0.f, 0.f, 0.f};
  if (bias) bb = *(const float4*)(bias + bx * 64 + tx * 4);
#pragma unroll
  for (int i = 0; i < 4; ++i) {
    int row = by * 64 + ty * 4 + i;
    float4 o;
    o.x = c[i][0] + bb.x; o.y = c[i][1] + bb.y;
    o.z = c[i][2] + bb.z; o.w = c[i][3] + bb.w;
    if (mode == 0) {
      *(float4*)(o0 + (size_t)row * N + bx * 64 + tx * 4) = o;
    } else {
      int b = row >> 10, t = row & 1023;
      int ch = bx;
      float* dst = o0;
      if (mode == 2 && bx >= 16) { ch = bx - 16; dst = o1; }
      *(float4*)(dst + ((size_t)((b * 16 + ch) * 1024 + t)) * 64 + tx * 4) = o;
    }
  }
}

// ---------------------------------------------------------------------------
// In-place RoPE on (b,h,t,d) buffer; angle index = (t & mask)
// ---------------------------------------------------------------------------
__global__ __launch_bounds__(TPB) void k_rope(float* __restrict__ A, int mask,
                                              const float* __restrict__ cosb,
                                              const float* __restrict__ sinb) {
  int gid = blockIdx.x * TPB + threadIdx.x;  // 65536 rows * 32
  int j = gid & 31;
  int row = gid >> 5;
  int t = row & 1023;
  int aidx = ((t & mask) << 5) + j;
  float cc = cosb[aidx], sn = sinb[aidx];
  size_t base = (size_t)row * 64;
  float x1 = A[base + 2 * j], x2 = A[base + 2 * j + 1];
  A[base + 2 * j] = x1 * cc - x2 * sn;
  A[base + 2 * j + 1] = x1 * sn + x2 * cc;
}

// ---------------------------------------------------------------------------
// Slide: gather overlapped key/value windows, rope K with local t.
// dst row (b,h,win*64+tl) <- src row (b,h,max(win*64-4,0)+tl)
// ---------------------------------------------------------------------------
__global__ __launch_bounds__(TPB) void k_gather(
    const float* __restrict__ K, const float* __restrict__ V,
    float* __restrict__ kc, float* __restrict__ vc,
    const float* __restrict__ cosb, const float* __restrict__ sinb) {
  int gid = blockIdx.x * TPB + threadIdx.x;  // 4*16*16*64*32 = 2097152
  int j = gid & 31;
  int tl = (gid >> 5) & 63;
  int win = (gid >> 11) & 15;
  int h = (gid >> 15) & 15;
  int b = gid >> 19;
  int sw = win * 64 - 4;
  if (win == 0) sw = 0;
  size_t bh = (size_t)(b * 16 + h) * 1024;
  size_t src = (bh + sw + tl) * 64;
  size_t dst = (bh + win * 64 + tl) * 64;
  int aidx = (tl << 5) + j;
  float cc = cosb[aidx], sn = sinb[aidx];
  float k1 = K[src + 2 * j], k2 = K[src + 2 * j + 1];
  kc[dst + 2 * j] = k1 * cc - k2 * sn;
  kc[dst + 2 * j + 1] = k1 * sn + k2 * cc;
  vc[dst + 2 * j] = V[src + 2 * j];
  vc[dst + 2 * j + 1] = V[src + 2 * j + 1];
}

// ---------------------------------------------------------------------------
// Per-iteration projections: qp=curq@Wlq+blq (store rms-norm'd to qph),
// kp=kc@Wlk+blk (raw back into kc, norm'd to kph), vp=vc@Wlv+blv (into vc).
// One block = 16 rows of one (win,b,h).
// ---------------------------------------------------------------------------
__global__ __launch_bounds__(TPB) void k_proj(
    const float* __restrict__ curq, float* __restrict__ kc,
    float* __restrict__ vc, float* __restrict__ qph, float* __restrict__ kph,
    const float* __restrict__ Wlq, const float* __restrict__ blq,
    const float* __restrict__ Wlk, const float* __restrict__ blk,
    const float* __restrict__ Wlv, const float* __restrict__ blv,
    const float* __restrict__ wln, int CQ, const int* __restrict__ flags) {
  int RT = CQ >> 4;
  int bid = blockIdx.x;
  int rt = bid % RT;
  int rest = bid / RT;
  int h = rest & 15; rest >>= 4;
  int b = rest & 3;
  int win = rest >> 2;
  if (flags && flags[win]) return;
  __shared__ float qs[16][68], ksm[16][68], vsm[16][68];
  int tid = threadIdx.x;
  int lr = tid >> 4, c4 = (tid & 15) * 4;
  size_t rowbase = (size_t)(b * 16 + h) * 1024 + (size_t)win * CQ + rt * 16;
  size_t g = (rowbase + lr) * 64 + c4;
  *(float4*)&qs[lr][c4] = *(const float4*)(curq + g);
  *(float4*)&ksm[lr][c4] = *(const float4*)(kc + g);
  *(float4*)&vsm[lr][c4] = *(const float4*)(vc + g);
  __syncthreads();
  int r = tid >> 4, cg = tid & 15;
  const float eps = 1.1920928955078125e-7f;
  float4 wl4 = *(const float4*)(wln + cg * 4);
  size_t orow = (rowbase + r) * 64 + cg * 4;
  float4 acc;
  float ssum, rms;
  // ---- Q
  acc = *(const float4*)(blq + cg * 4);
#pragma unroll 8
  for (int k = 0; k < 64; ++k) {
    float xv = qs[r][k];
    float4 w4 = *(const float4*)(Wlq + k * 64 + cg * 4);
    acc.x += xv * w4.x; acc.y += xv * w4.y;
    acc.z += xv * w4.z; acc.w += xv * w4.w;
  }
  ssum = acc.x * acc.x + acc.y * acc.y + acc.z * acc.z + acc.w * acc.w;
#pragma unroll
  for (int m = 1; m < 16; m <<= 1) ssum += __shfl_xor(ssum, m);
  rms = (float)(1.0 / sqrt((double)(ssum * 0.015625f + eps)));
  {
    float4 o;
    o.x = acc.x * rms * wl4.x; o.y = acc.y * rms * wl4.y;
    o.z = acc.z * rms * wl4.z; o.w = acc.w * rms * wl4.w;
    *(float4*)(qph + orow) = o;
  }
  // ---- K
  acc = *(const float4*)(blk + cg * 4);
#pragma unroll 8
  for (int k = 0; k < 64; ++k) {
    float xv = ksm[r][k];
    float4 w4 = *(const float4*)(Wlk + k * 64 + cg * 4);
    acc.x += xv * w4.x; acc.y += xv * w4.y;
    acc.z += xv * w4.z; acc.w += xv * w4.w;
  }
  *(float4*)(kc + orow) = acc;  // raw kp -> next kc
  ssum = acc.x * acc.x + acc.y * acc.y + acc.z * acc.z + acc.w * acc.w;
#pragma unroll
  for (int m = 1; m < 16; m <<= 1) ssum += __shfl_xor(ssum, m);
  rms = (float)(1.0 / sqrt((double)(ssum * 0.015625f + eps)));
  {
    float4 o;
    o.x = acc.x * rms * wl4.x; o.y = acc.y * rms * wl4.y;
    o.z = acc.z * rms * wl4.z; o.w = acc.w * rms * wl4.w;
    *(float4*)(kph + orow) = o;
  }
  // ---- V
  acc = *(const float4*)(blv + cg * 4);
#pragma unroll 8
  for (int k = 0; k < 64; ++k) {
    float xv = vsm[r][k];
    float4 w4 = *(const float4*)(Wlv + k * 64 + cg * 4);
    acc.x += xv * w4.x; acc.y += xv * w4.y;
    acc.z += xv * w4.z; acc.w += xv * w4.w;
  }
  *(float4*)(vc + orow) = acc;
}

// ---------------------------------------------------------------------------
// Attention (flash-style online softmax), 32 q-rows per block.
// mode 0 (it0): prev=attn, curq+=attn
// mode 1 (it1): curq+=attn, out=attn, diff partial = sum|attn - prev|
// mode 2 (it2): skip if flags[win], else out=attn
// ---------------------------------------------------------------------------
__global__ __launch_bounds__(TPB) void k_attn(
    const float* __restrict__ qph, const float* __restrict__ kph,
    const float* __restrict__ vbuf, float* __restrict__ curq,
    float* __restrict__ prevb, float* __restrict__ outb,
    float* __restrict__ diffp, const int* __restrict__ flags, int CQ,
    int mode) {
  int QT = CQ >> 5;
  int bid = blockIdx.x;
  int qt = bid % QT;
  int rest = bid / QT;
  int h = rest & 15; rest >>= 4;
  int b = rest & 3;
  int win = rest >> 2;
  if (mode == 2 && flags[win]) return;
  __shared__ float qs[32][68];
  __shared__ float ks[64][68];
  __shared__ float vs[64][68];
  __shared__ float red[256];
  float(*ps)[68] = qs;
  int tid = threadIdx.x;
  size_t bh1024 = (size_t)(b * 16 + h) * 1024;
  size_t qrow0 = bh1024 + (size_t)win * CQ + qt * 32;
  {
    int r = tid >> 3, cc = (tid & 7) * 8;
    const float* src = qph + (qrow0 + r) * 64 + cc;
    *(float4*)&qs[r][cc] = *(const float4*)src;
    *(float4*)&qs[r][cc + 4] = *(const float4*)(src + 4);
  }
  __syncthreads();
  int r8 = tid >> 3, j = tid & 7, cc8 = (tid & 7) * 8;
  float4 qreg[16];
#pragma unroll
  for (int k4 = 0; k4 < 16; ++k4) qreg[k4] = *(const float4*)&qs[r8][k4 * 4];
  __syncthreads();  // qs now reusable as ps
  float m = -INFINITY, l = 0.0f;
  float acc[8] = {0, 0, 0, 0, 0, 0, 0, 0};
  int NT = CQ >> 6;
  for (int kt = 0; kt < NT; ++kt) {
    size_t krow0 = bh1024 + (size_t)win * CQ + kt * 64;
    {
      int kr0 = tid >> 4, cc = (tid & 15) * 4;
#pragma unroll
      for (int i = 0; i < 4; ++i) {
        int kr = kr0 + i * 16;
        *(float4*)&ks[kr][cc] = *(const float4*)(kph + (krow0 + kr) * 64 + cc);
        *(float4*)&vs[kr][cc] = *(const float4*)(vbuf + (krow0 + kr) * 64 + cc);
      }
    }
    __syncthreads();
    float s8[8];
#pragma unroll
    for (int kk = 0; kk < 8; ++kk) {
      int key = kk * 8 + j;  // bank-conflict-free key assignment
      float4 d4 = {0.f, 0.f, 0.f, 0.f};
#pragma unroll
      for (int k4 = 0; k4 < 16; ++k4) {
        float4 kv = *(const float4*)&ks[key][k4 * 4];
        d4.x += qreg[k4].x * kv.x;
        d4.y += qreg[k4].y * kv.y;
        d4.z += qreg[k4].z * kv.z;
        d4.w += qreg[k4].w * kv.w;
      }
      s8[kk] = ((d4.x + d4.y) + (d4.z + d4.w)) * 0.125f;
    }
    float tmax = s8[0];
#pragma unroll
    for (int kk = 1; kk < 8; ++kk) tmax = fmaxf(tmax, s8[kk]);
#pragma unroll
    for (int mm = 1; mm < 8; mm <<= 1) tmax = fmaxf(tmax, __shfl_xor(tmax, mm));
    float mnew = fmaxf(m, tmax);
    float sc = expf(m - mnew);
    float psum = 0.0f;
#pragma unroll
    for (int kk = 0; kk < 8; ++kk) {
      float p = expf(s8[kk] - mnew);
      ps[r8][kk * 8 + j] = p;
      psum += p;
    }
#pragma unroll
    for (int mm = 1; mm < 8; mm <<= 1) psum += __shfl_xor(psum, mm);
    l = l * sc + psum;
    m = mnew;
#pragma unroll
    for (int c = 0; c < 8; ++c) acc[c] *= sc;
    __syncthreads();
#pragma unroll 8
    for (int kk = 0; kk < 64; ++kk) {
      float p = ps[r8][kk];
      float4 va = *(const float4*)&vs[kk][cc8];
      float4 vb = *(const float4*)&vs[kk][cc8 + 4];
      acc[0] += p * va.x; acc[1] += p * va.y;
      acc[2] += p * va.z; acc[3] += p * va.w;
      acc[4] += p * vb.x; acc[5] += p * vb.y;
      acc[6] += p * vb.z; acc[7] += p * vb.w;
    }
    __syncthreads();
  }
  float att[8];
#pragma unroll
  for (int c = 0; c < 8; ++c) att[c] = acc[c] / l;
  size_t base = (qrow0 + r8) * 64 + cc8;
  size_t t_out = (size_t)win * CQ + qt * 32 + r8;
  size_t obase = ((size_t)b * 1024 + t_out) * 1024 + h * 64 + cc8;
  if (mode == 0) {
#pragma unroll
    for (int c = 0; c < 8; ++c) {
      prevb[base + c] = att[c];
      curq[base + c] += att[c];
    }
  } else if (mode == 1) {
    float ds = 0.0f;
#pragma unroll
    for (int c = 0; c < 8; ++c) {
      ds += fabsf(att[c] - prevb[base + c]);
      curq[base + c] += att[c];
      outb[obase + c] = att[c];
    }
    red[tid] = ds;
    __syncthreads();
    for (int s = 128; s > 0; s >>= 1) {
      if (tid < s) red[tid] += red[tid + s];
      __syncthreads();
    }
    if (tid == 0) {
      int slot = ((win * 4 + b) * 16 + h) * QT + qt;
      diffp[slot] = red[0];
    }
  } else {
#pragma unroll
    for (int c = 0; c < 8; ++c) outb[obase + c] = att[c];
  }
}

// Deterministic fixed-order diff finalize -> per-window done flag
__global__ __launch_bounds__(64) void k_finalize(const float* __restrict__ diffp,
                                                 int* __restrict__ flags,
                                                 int nwin, int spw, float count) {
  int w = threadIdx.x;
  if (w < nwin) {
    float s = 0.0f;
    for (int i = 0; i < spw; ++i) s += diffp[w * spw + i];
    flags[w] = (s / count < 0.5f) ? 1 : 0;
  }
}

// ---------------------------------------------------------------------------
extern "C" void kernel_launch(void* const* d_in, const int* in_sizes, int n_in,
                              void* d_out, int out_size, void* d_ws,
                              size_t ws_size, hipStream_t stream) {
  const float* x = (const float*)d_in[0];
  const float* xa = (const float*)d_in[1];
  const float* wqn = (const float*)d_in[2];
  const float* Wq = (const float*)d_in[3];
  const float* bq = (const float*)d_in[4];
  const float* wkvn = (const float*)d_in[5];
  const float* Wkv = (const float*)d_in[6];
  const float* bkv = (const float*)d_in[7];
  const float* wln = (const float*)d_in[8];
  const float* Wlq = (const float*)d_in[9];
  const float* blq = (const float*)d_in[10];
  const float* Wlk = (const float*)d_in[11];
  const float* blk = (const float*)d_in[12];
  const float* Wlv = (const float*)d_in[13];
  const float* blv = (const float*)d_in[14];
  const float* Wo = (const float*)d_in[15];
  const float* bo = (const float*)d_in[16];

  float* ws = (float*)d_ws;
  const size_t SLOT = (size_t)4 * 16 * 1024 * 64;  // 4194304 f32 = 16 MiB
  float* xw = ws;                                  // needs 11*16 MiB = 176 MiB
  float* xaw = ws + SLOT;
  float* Q = ws + 2 * SLOT;  // also curq
  float* K = ws + 3 * SLOT;
  float* V = ws + 4 * SLOT;
  float* kc = ws + 5 * SLOT;
  float* vc = ws + 6 * SLOT;
  float* prev = ws + 7 * SLOT;
  float* qph = ws + 8 * SLOT;
  float* kph = ws + 9 * SLOT;
  float* misc = ws + 10 * SLOT;
  float* inv = misc;
  float* cosb = misc + 8192;
  float* sinb = cosb + 32768;
  float* diffp = sinb + 32768;
  int* flags = (int*)(diffp + 4096);

  k_tables<<<128, TPB, 0, stream>>>(cosb, sinb);

  for (int sl = 0; sl < 2; ++sl) {
    const float* Xin = sl ? xa : x;
    float* Xout = sl ? xaw : xw;
    k_rowinv<<<4096, TPB, 0, stream>>>(Xin, inv);
    k_gemm<<<dim3(16, 64), TPB, 0, stream>>>(Xin, inv, wqn, Wq, bq, Q, nullptr, 1024, 1);
    k_gemm<<<dim3(32, 64), TPB, 0, stream>>>(Xin, inv, wkvn, Wkv, bkv, K, V, 2048, 2);
    k_rope<<<8192, TPB, 0, stream>>>(Q, 63, cosb, sinb);
    k_gather<<<8192, TPB, 0, stream>>>(K, V, kc, vc, cosb, sinb);
    // it0
    k_proj<<<4096, TPB, 0, stream>>>(Q, kc, vc, qph, kph, Wlq, blq, Wlk, blk, Wlv, blv, wln, 64, nullptr);
    k_attn<<<2048, TPB, 0, stream>>>(qph, kph, vc, Q, prev, Xout, diffp, nullptr, 64, 0);
    // it1
    k_proj<<<4096, TPB, 0, stream>>>(Q, kc, vc, qph, kph, Wlq, blq, Wlk, blk, Wlv, blv, wln, 64, nullptr);
    k_attn<<<2048, TPB, 0, stream>>>(qph, kph, vc, Q, prev, Xout, diffp, nullptr, 64, 1);
    k_finalize<<<1, 64, 0, stream>>>(diffp, flags, 16, 128, 262144.0f);
    // it2 (skipped per-window when converged)
    k_proj<<<4096, TPB, 0, stream>>>(Q, kc, vc, qph, kph, Wlq, blq, Wlk, blk, Wlv, blv, wln, 64, flags);
    k_attn<<<2048, TPB, 0, stream>>>(qph, kph, vc, Q, prev, Xout, diffp, flags, 64, 2);
  }

  // final focus: cq = ck = 1024, single window
  k_rowinv<<<4096, TPB, 0, stream>>>(xw, inv);
  k_gemm<<<dim3(16, 64), TPB, 0, stream>>>(xw, inv, wqn, Wq, bq, Q, nullptr, 1024, 1);
  k_rowinv<<<4096, TPB, 0, stream>>>(xaw, inv);
  k_gemm<<<dim3(32, 64), TPB, 0, stream>>>(xaw, inv, wkvn, Wkv, bkv, K, V, 2048, 2);
  k_rope<<<8192, TPB, 0, stream>>>(Q, 1023, cosb, sinb);
  k_rope<<<8192, TPB, 0, stream>>>(K, 1023, cosb, sinb);
  float* fout = xw;  // xw consumed above; reuse as attention output
  k_proj<<<4096, TPB, 0, stream>>>(Q, K, V, qph, kph, Wlq, blq, Wlk, blk, Wlv, blv, wln, 1024, nullptr);
  k_attn<<<2048, TPB, 0, stream>>>(qph, kph, V, Q, prev, fout, diffp, nullptr, 1024, 0);
  k_proj<<<4096, TPB, 0, stream>>>(Q, K, V, qph, kph, Wlq, blq, Wlk, blk, Wlv, blv, wln, 1024, nullptr);
  k_attn<<<2048, TPB, 0, stream>>>(qph, kph, V, Q, prev, fout, diffp, nullptr, 1024, 1);
  k_finalize<<<1, 64, 0, stream>>>(diffp, flags, 1, 2048, 4194304.0f);
  k_proj<<<4096, TPB, 0, stream>>>(Q, K, V, qph, kph, Wlq, blq, Wlk, blk, Wlv, blv, wln, 1024, flags);
  k_attn<<<2048, TPB, 0, stream>>>(qph, kph, V, Q, prev, fout, diffp, flags, 1024, 2);

  k_gemm<<<dim3(16, 64), TPB, 0, stream>>>(fout, nullptr, nullptr, Wo, bo, (float*)d_out, nullptr, 1024, 0);
}